// Round 1
// baseline (14154.909 us; speedup 1.0000x reference)
//
#include <hip/hip_runtime.h>
#include <hip/hip_bf16.h>

#define SEQ 118
#define NBLK 8192

typedef __attribute__((ext_vector_type(8))) short short8;
typedef __attribute__((ext_vector_type(4))) float f32x4;

__device__ __forceinline__ f32x4 mfma16(short8 a, short8 b, f32x4 c){
  return __builtin_amdgcn_mfma_f32_16x16x32_bf16(a, b, c, 0, 0, 0);
}
__device__ __forceinline__ float bfr(float x){            // bf16 RNE round-trip
  return __bfloat162float(__float2bfloat16(x));
}
__device__ __forceinline__ float rsum16(float v){
  v += __shfl_xor(v,1); v += __shfl_xor(v,2); v += __shfl_xor(v,4); v += __shfl_xor(v,8);
  return v;
}
__device__ __forceinline__ float rmax16(float v){
  v = fmaxf(v, __shfl_xor(v,1)); v = fmaxf(v, __shfl_xor(v,2));
  v = fmaxf(v, __shfl_xor(v,4)); v = fmaxf(v, __shfl_xor(v,8));
  return v;
}

__global__ void prep_kernel(const float* __restrict__ qkv_w,
                            const float* __restrict__ fc2_w,
                            __hip_bfloat16* __restrict__ wbf){
  int i = blockIdx.x * 256 + threadIdx.x;   // 65536 total
  if (i < 384*128) wbf[i] = __float2bfloat16(qkv_w[i]);
  else             wbf[i] = __float2bfloat16(fc2_w[i - 384*128]);
}

__launch_bounds__(512)
__global__ void fused_kernel(const float* __restrict__ x,
                             const float* __restrict__ fc1_w, const float* __restrict__ fc1_b,
                             const float* __restrict__ qkv_b,
                             const float* __restrict__ fc2_b, const float* __restrict__ fc3_w,
                             const float* __restrict__ fc3_b,
                             const float* __restrict__ ln_g,  const float* __restrict__ ln_b,
                             const __hip_bfloat16* __restrict__ wqkv,   // [384][128] bf16
                             const __hip_bfloat16* __restrict__ wfc2,   // [128][128] bf16
                             float* __restrict__ out)
{
  // 32 KB activations / P-scratch; 32 KB each Q (also Y), K, V^T (head-major)
  __shared__ __hip_bfloat16 sA [128*128];
  __shared__ __hip_bfloat16 sQ [4*128*32];
  __shared__ __hip_bfloat16 sK [4*128*32];
  __shared__ __hip_bfloat16 sVt[4*32*128];
  __shared__ float sO1[128];
  __shared__ float sCb[896];   // qkv_b(384) fc2_b(128) fc3_w(128) ln_g(128) ln_b(128)

  const int b    = blockIdx.x;
  const int tid  = threadIdx.x;
  const int wv   = tid >> 6;        // wave 0..7 -> 16-row strip
  const int lane = tid & 63;
  const int c    = lane & 15;
  const int quad = lane >> 4;

  for (int i = tid; i < 896; i += 512){
    float v;
    if      (i < 384) v = qkv_b[i];
    else if (i < 512) v = fc2_b[i-384];
    else if (i < 640) v = fc3_w[i-512];
    else if (i < 768) v = ln_g [i-640];
    else              v = ln_b [i-768];
    sCb[i] = v;
  }
  { // h = silu(x*fc1_w + fc1_b); padded rows (s>=118) zeroed
    int s  = tid >> 2;
    int d0 = (tid & 3) * 32;
    float xs = (s < SEQ) ? x[b*SEQ + s] : 0.f;
    #pragma unroll 8
    for (int i = 0; i < 32; i++){
      int d = d0 + i;
      float v = 0.f;
      if (s < SEQ){
        float z = xs * fc1_w[d] + fc1_b[d];
        v = z / (1.f + __expf(-z));
      }
      sA[s*128 + d] = __float2bfloat16(v);
    }
  }
  __syncthreads();

  const float* sQB = sCb;
  const float* sFB = sCb + 384;
  const float* sW3 = sCb + 512;
  const float* sLG = sCb + 640;
  const float* sLB = sCb + 768;

  for (int p = 0; p < 2; ++p){
    // ================= QKV GEMM (M-strip per wave) =================
    short8 afr[4];
    #pragma unroll
    for (int k4 = 0; k4 < 4; k4++)
      afr[k4] = *(const short8*)(sA + (wv*16 + c)*128 + k4*32 + quad*8);

    // q & k tile-pairs (d, d+64) with RoPE epilogue
    for (int t = 0; t < 4; ++t){
      const int d0 = t*16 + c;                      // 0..63
      f32x4 aq0={0,0,0,0}, aq1={0,0,0,0}, ak0={0,0,0,0}, ak1={0,0,0,0};
      #pragma unroll
      for (int k4 = 0; k4 < 4; k4++){
        const __hip_bfloat16* wp = wqkv + k4*32 + quad*8;
        short8 b0 = *(const short8*)(wp + (d0      )*128);
        short8 b1 = *(const short8*)(wp + (d0 +  64)*128);
        short8 b2 = *(const short8*)(wp + (d0 + 128)*128);
        short8 b3 = *(const short8*)(wp + (d0 + 192)*128);
        aq0 = mfma16(afr[k4], b0, aq0);
        aq1 = mfma16(afr[k4], b1, aq1);
        ak0 = mfma16(afr[k4], b2, ak0);
        ak1 = mfma16(afr[k4], b3, ak1);
      }
      float bq0 = sQB[d0], bq1 = sQB[d0+64], bk0 = sQB[128+d0], bk1 = sQB[192+d0];
      float invf = exp2f((float)d0 * (-13.287712379549449f/64.f)); // 10000^(-d0/64)
      int hh = d0 & 3, dh = d0 >> 2;
      __hip_bfloat16* q_p = sQ + hh*4096;
      __hip_bfloat16* k_p = sK + hh*4096;
      #pragma unroll
      for (int j = 0; j < 4; j++){
        int s = wv*16 + quad*4 + j;
        float ang = (float)s * invf;
        float cv = bfr(__cosf(ang));
        float sv = bfr(__sinf(ang));
        float q1 = aq0[j] + bq0, q2 = aq1[j] + bq1;
        float k1 = ak0[j] + bk0, k2 = ak1[j] + bk1;
        q_p[s*32 + dh     ] = __float2bfloat16( q1*cv + q2*sv);
        q_p[s*32 + dh + 16] = __float2bfloat16(-q1*sv + q2*cv);
        k_p[s*32 + dh     ] = __float2bfloat16( k1*cv + k2*sv);
        k_p[s*32 + dh + 16] = __float2bfloat16(-k1*sv + k2*cv);
      }
    }
    // v tiles -> transposed store sVt[h][dh][s]
    for (int t = 0; t < 8; ++t){
      const int d0 = t*16 + c;                      // 0..127
      f32x4 av = {0,0,0,0};
      #pragma unroll
      for (int k4 = 0; k4 < 4; k4++){
        short8 bv = *(const short8*)(wqkv + (256 + d0)*128 + k4*32 + quad*8);
        av = mfma16(afr[k4], bv, av);
      }
      float bias = sQB[256 + d0];
      int hh = d0 & 3, dh = d0 >> 2;
      __hip_bfloat16* vp = sVt + hh*4096 + dh*128 + wv*16 + quad*4;
      #pragma unroll
      for (int j = 0; j < 4; j++) vp[j] = __float2bfloat16(av[j] + bias);
    }
    __syncthreads();   // Q/K/Vt visible to all waves

    // ================= attention (no barriers inside) =================
    for (int h = 0; h < 4; ++h){
      const int st = (h & 1) ? (7 - wv) : wv;       // balanced causal strips
      short8 aq = *(const short8*)(sQ + h*4096 + (st*16 + c)*32 + quad*8);
      f32x4 sc[8];
      #pragma unroll
      for (int t = 0; t < 8; ++t){
        if (t <= st){
          short8 bk = *(const short8*)(sK + h*4096 + (t*16 + c)*32 + quad*8);
          f32x4 z = {0,0,0,0};
          sc[t] = mfma16(aq, bk, z);
        }
      }
      const int ntp = (st + 2) & ~1;                // P tiles padded to even
      const float scale = 0.17677669529663687f;     // 1/sqrt(32)
      #pragma unroll
      for (int j = 0; j < 4; j++){
        const int s = st*16 + quad*4 + j;
        float mx = -3.0e38f;
        #pragma unroll
        for (int t = 0; t < 8; t++){
          if (t <= st){
            float v = ((t*16 + c) <= s) ? sc[t][j]*scale : -1.0e9f;
            sc[t][j] = v;
            mx = fmaxf(mx, v);
          }
        }
        mx = rmax16(mx);
        float sum = 0.f;
        #pragma unroll
        for (int t = 0; t < 8; t++){
          if (t <= st){
            float e = __expf(sc[t][j] - mx);
            sc[t][j] = e;
            sum += e;
          }
        }
        sum = rsum16(sum);
        float r = 1.f / sum;
        #pragma unroll
        for (int t = 0; t < 8; t++){
          if (t < ntp){
            float pv = (t <= st) ? sc[t][j]*r : 0.f; // zero-pad odd tile
            sA[(wv*16 + quad*4 + j)*128 + t*16 + c] = __float2bfloat16(pv);
          }
        }
      }
      // P @ V  (P rows indexed by WAVE -> race-free across heads)
      f32x4 y0 = {0,0,0,0}, y1 = {0,0,0,0};
      const int K4 = ntp >> 1;
      #pragma unroll
      for (int kk = 0; kk < 4; kk++){
        if (kk < K4){
          short8 ap  = *(const short8*)(sA  + (wv*16 + c)*128 + kk*32 + quad*8);
          short8 bv0 = *(const short8*)(sVt + h*4096 + (c     )*128 + kk*32 + quad*8);
          short8 bv1 = *(const short8*)(sVt + h*4096 + (16 + c)*128 + kk*32 + quad*8);
          y0 = mfma16(ap, bv0, y0);
          y1 = mfma16(ap, bv1, y1);
        }
      }
      #pragma unroll
      for (int j = 0; j < 4; j++){
        int s = st*16 + quad*4 + j;
        sQ[h*4096 + s*32 + c     ] = __float2bfloat16(y0[j]);   // Y overwrites Q
        sQ[h*4096 + s*32 + 16 + c] = __float2bfloat16(y1[j]);
      }
    }
    __syncthreads();   // Y strips written by two waves each -> fc2 needs all

    // ================= FC2 + fused epilogue =================
    short8 ay[4];
    #pragma unroll
    for (int k4 = 0; k4 < 4; k4++)
      ay[k4] = *(const short8*)(sQ + k4*4096 + (wv*16 + c)*32 + quad*8);
    f32x4 xx[8];
    #pragma unroll
    for (int t = 0; t < 8; t++){
      f32x4 acc = {0,0,0,0};
      #pragma unroll
      for (int k4 = 0; k4 < 4; k4++){
        short8 bw = *(const short8*)(wfc2 + (t*16 + c)*128 + k4*32 + quad*8);
        acc = mfma16(ay[k4], bw, acc);
      }
      float bias = sFB[t*16 + c];
      #pragma unroll
      for (int j = 0; j < 4; j++){
        float z = acc[j] + bias;
        xx[t][j] = z / (1.f + __expf(-z));          // silu
      }
    }
    #pragma unroll
    for (int j = 0; j < 4; j++){
      float s1 = 0.f, s2 = 0.f, s3 = 0.f;
      #pragma unroll
      for (int t = 0; t < 8; t++){
        float v = xx[t][j];
        s1 += v; s2 += v*v; s3 += v * sW3[t*16 + c];
      }
      s1 = rsum16(s1); s2 = rsum16(s2); s3 = rsum16(s3);
      const int s = wv*16 + quad*4 + j;
      if (p == 0){
        float mu  = s1 * (1.f/128.f);
        float var = fmaxf(s2 * (1.f/128.f) - mu*mu, 0.f);  // clamp: NaN guard
        float rs  = rsqrtf(var + 1e-5f);
        #pragma unroll
        for (int t = 0; t < 8; t++){
          int d = t*16 + c;
          sA[s*128 + d] = __float2bfloat16((xx[t][j] - mu)*rs*sLG[d] + sLB[d]);
        }
        if (c == 0) sO1[s] = s3;                    // x1 . fc3_w  (residual readout)
      } else {
        if (c == 0 && s < SEQ) out[b*SEQ + s] = sO1[s] + s3 + fc3_b[0];
      }
    }
    // no barrier needed: all cross-pass LDS hand-offs are wave-private strips
  }
}

extern "C" void kernel_launch(void* const* d_in, const int* in_sizes, int n_in,
                              void* d_out, int out_size, void* d_ws, size_t ws_size,
                              hipStream_t stream){
  const float* x     = (const float*)d_in[0];
  const float* fc1_w = (const float*)d_in[1];
  const float* fc1_b = (const float*)d_in[2];
  const float* qkv_w = (const float*)d_in[3];
  const float* qkv_b = (const float*)d_in[4];
  const float* fc2_w = (const float*)d_in[5];
  const float* fc2_b = (const float*)d_in[6];
  const float* fc3_w = (const float*)d_in[7];
  const float* fc3_b = (const float*)d_in[8];
  const float* ln_g  = (const float*)d_in[9];
  const float* ln_b  = (const float*)d_in[10];

  __hip_bfloat16* wbf = (__hip_bfloat16*)d_ws;        // 384*128 + 128*128 bf16
  prep_kernel<<<256, 256, 0, stream>>>(qkv_w, fc2_w, wbf);

  const int B = in_sizes[0] / SEQ;                    // 8192
  fused_kernel<<<B, 512, 0, stream>>>(x, fc1_w, fc1_b, qkv_b, fc2_b, fc3_w, fc3_b,
                                      ln_g, ln_b, wbf, wbf + 384*128, (float*)d_out);
}